// Round 4
// baseline (235.425 us; speedup 1.0000x reference)
//
#include <hip/hip_runtime.h>
#include <math.h>
#include <stdint.h>

#define IMG_H 2048
#define IMG_W 2048
#define NB    8
#define BORDER 10
#define REP_THR 0.6f
#define ROWS  6            // output rows per block (slab height)
#define SROWS (ROWS + 2)   // staged input rows = 8  -> 64 KiB LDS
#define SLABS 342          // ceil(2048 / 6); last slab row-clipped

typedef float f32x4 __attribute__((ext_vector_type(4)));

// Block-tiled NMS with async global->LDS staging.
//
// WHY: rounds 1-3 proved the kernel is latency-bound (~80us vs ~45us
// roofline; HBM 33%, VALU 9%, nothing saturated) and that the AMDGPU
// register allocator will NOT keep >~4 global loads in flight per wave
// (VGPR_Count stayed 32-40 despite sched_barrier + launch_bounds).
// __builtin_amdgcn_global_load_lds sidesteps the allocator: loads go
// straight to LDS with NO destination VGPRs, so each wave issues 16 x 1KB
// loads back-to-back (16KB in flight/wave, 128KB/CU) and __syncthreads
// drains them once. MLP is now structural, not allocator-dependent.
//
// Layout: each block = 256 threads stages SROWS=8 full 2048-col rows
// (64 chunks of 1KB; wave w stages chunks 16w..16w+15) and computes a
// 6-row x 2048-col output slab. Halo values come from LDS, so the global
// path is pure 1KB-coalesced reads (no scalar halo loads at all).
//
// Staged row indices clamp to [BORDER-1, IMG_H-BORDER] = [9, 2038]: rows
// outside only feed border-masked outputs (verified: unmasked output row y
// needs rows y-1..y+1, all inside [9,2038]).
//
// XCD swizzle: 2736 blocks = 8 XCDs x 342 -> each XCD owns exactly one
// image; vertically-adjacent slabs (sharing 2 halo rows) stay on one XCD's
// L2 instead of round-robining across chiplets.
__global__ __launch_bounds__(256) void nms_kernel(const float* __restrict__ in,
                                                  float* __restrict__ out) {
    __shared__ float tile[SROWS][IMG_W];   // 8 * 2048 * 4B = 65536 B

    const int nwg  = NB * SLABS;           // 2736, divisible by 8
    const int orig = blockIdx.x;
    const int swz  = (orig & 7) * (nwg >> 3) + (orig >> 3);
    const int b    = swz / SLABS;          // image  (== orig & 7)
    const int slab = swz % SLABS;          // 0..341 (== orig >> 3)
    const int y0   = slab * ROWS;          // 0, 6, ..., 2046

    const int t    = threadIdx.x;
    const int lane = t & 63;
    const int wave = t >> 6;

    const size_t img_off = (size_t)b * IMG_H * IMG_W;
    const float* ibase = in + img_off;

    // ---- Stage 8 rows into LDS: 64 x 1KB async direct-to-LDS loads ----
#pragma unroll
    for (int i = 0; i < 16; ++i) {
        const int k = wave * 16 + i;   // chunk id 0..63 (wave-uniform)
        const int r = k >> 3;          // staged row 0..7
        const int cc = k & 7;          // 256-float chunk within the row
        int g = y0 - 1 + r;
        g = g < (BORDER - 1) ? (BORDER - 1)
          : (g > (IMG_H - BORDER) ? (IMG_H - BORDER) : g);
        const float* src = ibase + (size_t)g * IMG_W + (cc << 8) + (lane << 2);
        float* dst = &tile[r][cc << 8];   // wave-uniform; HW adds lane*16
        __builtin_amdgcn_global_load_lds(
            (const __attribute__((address_space(1))) void*)src,
            (__attribute__((address_space(3))) void*)dst,
            16, 0, 0);
    }
    __syncthreads();   // compiler emits the vmcnt(0) drain here

    // ---- Compute: 2 column passes (cols 4t and 4t+1024), 6 rows each ----
#pragma unroll
    for (int p = 0; p < 2; ++p) {
        const int c0 = (t << 2) + (p << 10);               // 0..2044, 16B-aligned
        const int cl = (c0 == 0) ? 0 : c0 - 1;             // clamped halo cols:
        const int cr = (c0 + 4 < IMG_W) ? c0 + 4 : IMG_W - 1;  // only border cols
                                                           // affected -> masked
        f32x4 v[SROWS], h[SROWS];
#pragma unroll
        for (int r = 0; r < SROWS; ++r) {
            v[r] = *(const f32x4*)&tile[r][c0];
            const float l = tile[r][cl];
            const float q = tile[r][cr];
            h[r][0] = fmaxf(l,       fmaxf(v[r][0], v[r][1]));
            h[r][1] = fmaxf(v[r][0], fmaxf(v[r][1], v[r][2]));
            h[r][2] = fmaxf(v[r][1], fmaxf(v[r][2], v[r][3]));
            h[r][3] = fmaxf(v[r][2], fmaxf(v[r][3], q));
        }

        const bool bx0 = (c0 + 0 >= BORDER) && (c0 + 0 < IMG_W - BORDER);
        const bool bx1 = (c0 + 1 >= BORDER) && (c0 + 1 < IMG_W - BORDER);
        const bool bx2 = (c0 + 2 >= BORDER) && (c0 + 2 < IMG_W - BORDER);
        const bool bx3 = (c0 + 3 >= BORDER) && (c0 + 3 < IMG_W - BORDER);

        float* obase = out + img_off + (size_t)y0 * IMG_W + c0;
#pragma unroll
        for (int j = 0; j < ROWS; ++j) {
            const int y = y0 + j;
            if (y < IMG_H) {   // block-uniform branch (last slab clips rows)
                const bool rowok = (y >= BORDER) && (y < IMG_H - BORDER);

                f32x4 m;
                m[0] = fmaxf(h[j][0], fmaxf(h[j + 1][0], h[j + 2][0]));
                m[1] = fmaxf(h[j][1], fmaxf(h[j + 1][1], h[j + 2][1]));
                m[2] = fmaxf(h[j][2], fmaxf(h[j + 1][2], h[j + 2][2]));
                m[3] = fmaxf(h[j][3], fmaxf(h[j + 1][3], h[j + 2][3]));

                const f32x4 c = v[j + 1];
                f32x4 r;
                r[0] = (c[0] == m[0] && c[0] >= REP_THR && bx0 && rowok) ? 1.f : 0.f;
                r[1] = (c[1] == m[1] && c[1] >= REP_THR && bx1 && rowok) ? 1.f : 0.f;
                r[2] = (c[2] == m[2] && c[2] >= REP_THR && bx2 && rowok) ? 1.f : 0.f;
                r[3] = (c[3] == m[3] && c[3] >= REP_THR && bx3 && rowok) ? 1.f : 0.f;

                __builtin_nontemporal_store(r, (f32x4*)(obase + (size_t)j * IMG_W));
            }
        }
    }
}

extern "C" void kernel_launch(void* const* d_in, const int* in_sizes, int n_in,
                              void* d_out, int out_size, void* d_ws, size_t ws_size,
                              hipStream_t stream) {
    const float* in = (const float*)d_in[0];
    float* out = (float*)d_out;
    const int grid = NB * SLABS;   // 2736 blocks
    nms_kernel<<<grid, 256, 0, stream>>>(in, out);
}

// Round 5
// 229.713 us; speedup vs baseline: 1.0249x; 1.0249x over previous
//
#include <hip/hip_runtime.h>
#include <math.h>

#define IMG_H 2048
#define IMG_W 2048
#define NB    8
#define BORDER 10
#define REP_THR 0.6f

typedef float f32x4 __attribute__((ext_vector_type(4)));

// Copy-shaped NMS: one thread per float4 of OUTPUT (2^23 threads, 32x wave
// oversubscription). Rationale from rounds 1-4: every attempt to raise
// per-thread MLP (hoisted batches, sched_barrier, launch_bounds, async
// global->LDS staging) plateaued at 75-85us because the allocator caps
// per-wave loads in flight (~VGPR 32-40) or barriers serialize phases.
// Meanwhile fillBuffer (8 VGPR, 10% occupancy) and the m13 copy ubench
// (trivial grid-stride float4) both stream at 6.3-6.7 TB/s. The winning
// profile is copy-shaped: minimal per-thread state, maximal TLP, zero
// barriers. This kernel: 3 float4 loads (rows y-1,y,y+1) + 6 scalar halo
// loads (same cache lines -> L1 hits), ~30 VALU ops, 1 nontemporal store.
//
// Vertical reuse: each input line is demanded by output rows y-1,y,y+1 --
// blocks at most 4 apart in dispatch order. XCD swizzle (32768 blocks =
// 8 XCDs x 4096; image k -> XCD k) keeps those re-reads inside one XCD's
// 4 MiB L2 (holds ~500 rows), so HBM-side read traffic stays ~1.0x.
//
// Border: rows [0,10) u [2038,2048) and col-groups 0/511 write zeros with
// no loads. Interior threads need rows y-1..y+1 in [9,2038] -- always in
// bounds, so the hot path has no clamps and no divergence at all.
__global__ __launch_bounds__(256) void nms_kernel(const float* __restrict__ in,
                                                  float* __restrict__ out) {
    // XCD-aware block swizzle: 32768 blocks, 8 XCDs, 4096 contiguous
    // blocks (= exactly one image) per XCD.
    const int orig = blockIdx.x;
    const int swz  = (orig & 7) * 4096 + (orig >> 3);
    const int tid  = (swz << 8) | threadIdx.x;   // 0 .. 2^23-1

    const int gx = tid & 511;           // float4 index within row
    const int y  = (tid >> 9) & 2047;   // row
    const int b  = tid >> 20;           // image

    const int x4 = gx << 2;             // 0..2044

    const size_t img_off = (size_t)b * IMG_H * IMG_W;
    float* optr = out + img_off + (size_t)y * IMG_W + x4;

    // Zero-only threads: row border or column-border float4 groups.
    if (y < BORDER || y >= IMG_H - BORDER || gx == 0 || gx == 511) {
        const f32x4 z = {0.f, 0.f, 0.f, 0.f};
        __builtin_nontemporal_store(z, (f32x4*)optr);
        return;
    }

    const float* base = in + img_off + (size_t)y * IMG_W + x4;
    const float* r0 = base - IMG_W;
    const float* r1 = base;
    const float* r2 = base + IMG_W;

    // Three rows: aligned float4 + left/right scalar halos (L1 hits).
    const f32x4 v0 = *(const f32x4*)r0;
    const f32x4 v1 = *(const f32x4*)r1;
    const f32x4 v2 = *(const f32x4*)r2;
    const float l0 = r0[-1], q0 = r0[4];
    const float l1 = r1[-1], q1 = r1[4];
    const float l2 = r2[-1], q2 = r2[4];

    // Horizontal 3-max per row (clang fuses fmaxf pairs to v_max3_f32).
    f32x4 h0, h1, h2;
    h0[0] = fmaxf(l0,    fmaxf(v0[0], v0[1]));
    h0[1] = fmaxf(v0[0], fmaxf(v0[1], v0[2]));
    h0[2] = fmaxf(v0[1], fmaxf(v0[2], v0[3]));
    h0[3] = fmaxf(v0[2], fmaxf(v0[3], q0));
    h1[0] = fmaxf(l1,    fmaxf(v1[0], v1[1]));
    h1[1] = fmaxf(v1[0], fmaxf(v1[1], v1[2]));
    h1[2] = fmaxf(v1[1], fmaxf(v1[2], v1[3]));
    h1[3] = fmaxf(v1[2], fmaxf(v1[3], q1));
    h2[0] = fmaxf(l2,    fmaxf(v2[0], v2[1]));
    h2[1] = fmaxf(v2[0], fmaxf(v2[1], v2[2]));
    h2[2] = fmaxf(v2[1], fmaxf(v2[2], v2[3]));
    h2[3] = fmaxf(v2[2], fmaxf(v2[3], q2));

    // Vertical 3-max.
    f32x4 m;
    m[0] = fmaxf(h0[0], fmaxf(h1[0], h2[0]));
    m[1] = fmaxf(h0[1], fmaxf(h1[1], h2[1]));
    m[2] = fmaxf(h0[2], fmaxf(h1[2], h2[2]));
    m[3] = fmaxf(h0[3], fmaxf(h1[3], h2[3]));

    // Column border mask (rows already known interior).
    const bool bx0 = (x4 + 0 >= BORDER) && (x4 + 0 < IMG_W - BORDER);
    const bool bx1 = (x4 + 1 >= BORDER) && (x4 + 1 < IMG_W - BORDER);
    const bool bx2 = (x4 + 2 >= BORDER) && (x4 + 2 < IMG_W - BORDER);
    const bool bx3 = (x4 + 3 >= BORDER) && (x4 + 3 < IMG_W - BORDER);

    f32x4 r;
    r[0] = (v1[0] == m[0] && v1[0] >= REP_THR && bx0) ? 1.f : 0.f;
    r[1] = (v1[1] == m[1] && v1[1] >= REP_THR && bx1) ? 1.f : 0.f;
    r[2] = (v1[2] == m[2] && v1[2] >= REP_THR && bx2) ? 1.f : 0.f;
    r[3] = (v1[3] == m[3] && v1[3] >= REP_THR && bx3) ? 1.f : 0.f;

    __builtin_nontemporal_store(r, (f32x4*)optr);
}

extern "C" void kernel_launch(void* const* d_in, const int* in_sizes, int n_in,
                              void* d_out, int out_size, void* d_ws, size_t ws_size,
                              hipStream_t stream) {
    const float* in = (const float*)d_in[0];
    float* out = (float*)d_out;
    const int total_threads = NB * IMG_H * (IMG_W / 4);  // 2^23
    const int block = 256;
    const int grid = total_threads / block;              // 32768
    nms_kernel<<<grid, block, 0, stream>>>(in, out);
}